// Round 6
// baseline (241.256 us; speedup 1.0000x reference)
//
#include <hip/hip_runtime.h>
#include <cstdint>

#define VOCAB 100000
#define NB    2048
#define SEQ   50
#define HID   256
#define XIN   512
#define NE    64
#define NP    5

#define OFF_BOW_E 0
#define OFF_BEO_E (NB*NE)
#define OFF_BOW_P (2*NB*NE)
#define OFF_BEO_P (2*NB*NE + NB*NP)

// ================= bow kernel: 1024 threads (16 waves) per row =============
// R1-R5 lesson: compiler insists on ~2 live gather slots per wave (VGPR 52-56
// across 4 structures). Robust fix: only 4 tokens per wave -> worst-case
// serial chain 4 x ~375ns, and 2048x16 independent wave-gathers feed the
// memory system regardless of per-wave MLP.
#define BOW_T   1024
#define BOW_W   16
#define BOW_TPW 4      // token idx i = w + 16*ii -> 0..63 (i>=SEQ masked off)

__global__ __launch_bounds__(BOW_T, 4) void bow_kernel(
    const int*   __restrict__ s,   const float* __restrict__ Wbh,
    const float* __restrict__ bbh,
    const float* __restrict__ Wbp, const float* __restrict__ bbp,
    const float* __restrict__ Wbe, const float* __restrict__ bbe,
    float* __restrict__ out)
{
    __shared__ float part[BOW_W*HID];   // 16 KB; reused for head partials
    __shared__ float h[HID];
    const int tid  = threadIdx.x;
    const int row  = blockIdx.x;
    const int lane = tid & 63;
    const int w    = tid >> 6;
    const int* srow = s + row*SEQ;

    // lane j holds token j (j<50); others -3 (never matches a valid token)
    int tokl = (lane < SEQ) ? srow[lane] : -3;

    int   tk[BOW_TPW];
    float mk[BOW_TPW];
    #pragma unroll
    for (int ii = 0; ii < BOW_TPW; ++ii) {
        const int i = w + BOW_W*ii;              // this wave's token index
        int t = (i < SEQ) ? srow[i] : -3;
        t = __builtin_amdgcn_readfirstlane(t);
        unsigned long long dup = __ballot(lane < i && tokl == t);
        mk[ii] = (t >= 0 && dup == 0ull) ? 1.0f : 0.0f;  // keep 1st occurrence
        tk[ii] = (t < 0) ? 0 : t;
    }

    // 4 x 1KB row-gathers (lane l -> cols 4l..4l+3)
    float4 v[BOW_TPW];
    const float* wbase = Wbh + (size_t)lane*4;
    #pragma unroll
    for (int ii = 0; ii < BOW_TPW; ++ii)
        v[ii] = *(const float4*)(wbase + (size_t)tk[ii]*HID);
    __builtin_amdgcn_sched_barrier(0);

    float ax=0.f, ay=0.f, az=0.f, aw_=0.f;
    #pragma unroll
    for (int ii = 0; ii < BOW_TPW; ++ii) {
        ax = fmaf(mk[ii], v[ii].x, ax);
        ay = fmaf(mk[ii], v[ii].y, ay);
        az = fmaf(mk[ii], v[ii].z, az);
        aw_= fmaf(mk[ii], v[ii].w, aw_);
    }
    *(float4*)&part[w*HID + lane*4] = make_float4(ax, ay, az, aw_);
    __syncthreads();

    if (tid < HID) {
        float hv = bbh[tid];
        #pragma unroll
        for (int p = 0; p < BOW_W; ++p) hv += part[p*HID + tid];
        hv = hv > 0.f ? hv : 0.2f*hv;
        h[tid] = hv;
    }
    __syncthreads();

    // embd head: 64 outs x 16 partials = 1024 threads
    {
        const int jj = tid & 63, p2 = tid >> 6;   // p2 in 0..15
        float ps = 0.f;
        #pragma unroll
        for (int kk = 0; kk < 16; ++kk) {
            int k = p2*16 + kk;
            ps = fmaf(h[k], Wbe[k*NE + jj], ps);
        }
        part[tid] = ps;                           // flat [p2*64+jj]
    }
    // pred partials: 5 outs x 8 partials (threads 0..39)
    float pp = 0.f;
    if (tid < 8*NP) {
        const int p = tid / NP, jj = tid % NP;
        #pragma unroll 8
        for (int kk = 0; kk < 32; ++kk) {
            int k = p*32 + kk;
            pp = fmaf(h[k], Wbp[k*NP + jj], pp);
        }
    }
    __syncthreads();
    if (tid < NE) {
        float e = bbe[tid];
        #pragma unroll
        for (int p2 = 0; p2 < 16; ++p2) e += part[p2*64 + tid];
        out[OFF_BOW_E + (size_t)row*NE + tid] = e;
    }
    __syncthreads();                              // part free again
    if (tid < 8*NP) part[tid] = pp;
    __syncthreads();
    if (tid < NP) {
        float sp = bbp[tid];
        #pragma unroll
        for (int q = 0; q < 8; ++q) sp += part[q*NP + tid];
        out[OFF_BOW_P + (size_t)row*NP + tid] = sp;
    }
}

// ================= beo kernel: R5's proven path, standalone ================
#define BEO_BLOCKS 256
#define BEO_ROWS   8

__global__ __launch_bounds__(256, 1) void beo_kernel(
    const float* __restrict__ x,
    const float* __restrict__ Weh, const float* __restrict__ beh,
    const float* __restrict__ Wep, const float* __restrict__ bep,
    const float* __restrict__ Wee, const float* __restrict__ bee,
    float* __restrict__ out)
{
    __shared__ float xs[BEO_ROWS*XIN];            // 16 KB (reused as hs)
    const int tid = threadIdx.x;
    const int r0  = blockIdx.x * BEO_ROWS;
    {
        const float4* src = (const float4*)(x + (size_t)r0 * XIN);
        float4*       dst = (float4*)xs;
        #pragma unroll
        for (int i = 0; i < (BEO_ROWS*XIN/4)/256; ++i)
            dst[i*256 + tid] = src[i*256 + tid];
    }
    __syncthreads();

    float acc[BEO_ROWS];
    {
        float bv = beh[tid];
        #pragma unroll
        for (int r = 0; r < BEO_ROWS; ++r) acc[r] = bv;
    }
    const float4* xs4 = (const float4*)xs;        // [r*(XIN/4)+k4]
    #pragma unroll 2
    for (int k4 = 0; k4 < XIN/4; ++k4) {
        const float* wcol = Weh + (size_t)(4*k4)*HID + tid;
        float w0 = wcol[0];
        float w1 = wcol[HID];
        float w2 = wcol[2*HID];
        float w3 = wcol[3*HID];
        #pragma unroll
        for (int r = 0; r < BEO_ROWS; ++r) {
            float4 xv = xs4[r*(XIN/4) + k4];
            acc[r] = fmaf(xv.x, w0, acc[r]);
            acc[r] = fmaf(xv.y, w1, acc[r]);
            acc[r] = fmaf(xv.z, w2, acc[r]);
            acc[r] = fmaf(xv.w, w3, acc[r]);
        }
    }
    __syncthreads();
    float* hs = xs;                                // reuse as hs[8][256]
    #pragma unroll
    for (int r = 0; r < BEO_ROWS; ++r) {
        float vv = acc[r];
        hs[r*HID + tid] = vv > 0.f ? vv : 0.2f*vv;
    }
    __syncthreads();

    // embd head: 8 rows x 64 cols -> 2 outputs per thread (float4 form)
    {
        const int jj = tid & 63;
        const int r  = tid >> 6;                   // rows r and r+4
        const float4* hs4 = (const float4*)hs;
        float s0 = 0.f, s1 = 0.f;
        #pragma unroll 4
        for (int k4 = 0; k4 < HID/4; ++k4) {
            float4 ha = hs4[r*(HID/4) + k4];
            float4 hb = hs4[(r+4)*(HID/4) + k4];
            const float* wp = Wee + (size_t)(4*k4)*NE + jj;
            float w0 = wp[0], w1 = wp[NE], w2 = wp[2*NE], w3 = wp[3*NE];
            s0 = fmaf(ha.x, w0, s0); s0 = fmaf(ha.y, w1, s0);
            s0 = fmaf(ha.z, w2, s0); s0 = fmaf(ha.w, w3, s0);
            s1 = fmaf(hb.x, w0, s1); s1 = fmaf(hb.y, w1, s1);
            s1 = fmaf(hb.z, w2, s1); s1 = fmaf(hb.w, w3, s1);
        }
        float bias = bee[jj];
        out[OFF_BEO_E + (size_t)(r0+r)*NE   + jj] = s0 + bias;
        out[OFF_BEO_E + (size_t)(r0+r+4)*NE + jj] = s1 + bias;
    }
    // pred head: 8 rows x 5 cols
    if (tid < BEO_ROWS*NP) {
        const int r = tid / NP, jj = tid % NP;
        float sp = bep[jj];
        for (int k = 0; k < HID; ++k)
            sp = fmaf(hs[r*HID + k], Wep[k*NP + jj], sp);
        out[OFF_BEO_P + (size_t)(r0+r)*NP + jj] = sp;
    }
}

extern "C" void kernel_launch(void* const* d_in, const int* in_sizes, int n_in,
                              void* d_out, int out_size, void* d_ws, size_t ws_size,
                              hipStream_t stream) {
    const int*   s   = (const int*)  d_in[0];
    const float* x   = (const float*)d_in[1];
    const float* Wbh = (const float*)d_in[2];
    const float* bbh = (const float*)d_in[3];
    const float* Wbp = (const float*)d_in[4];
    const float* bbp = (const float*)d_in[5];
    const float* Wbe = (const float*)d_in[6];
    const float* bbe = (const float*)d_in[7];
    const float* Weh = (const float*)d_in[8];
    const float* beh = (const float*)d_in[9];
    const float* Wep = (const float*)d_in[10];
    const float* bep = (const float*)d_in[11];
    const float* Wee = (const float*)d_in[12];
    const float* bee = (const float*)d_in[13];
    float* out = (float*)d_out;

    bow_kernel<<<dim3(NB), dim3(BOW_T), 0, stream>>>(
        s, Wbh, bbh, Wbp, bbp, Wbe, bbe, out);
    beo_kernel<<<dim3(BEO_BLOCKS), dim3(256), 0, stream>>>(
        x, Weh, beh, Wep, bep, Wee, bee, out);
}

// Round 7
// 232.194 us; speedup vs baseline: 1.0390x; 1.0390x over previous
//
#include <hip/hip_runtime.h>
#include <cstdint>

typedef float f32x4 __attribute__((ext_vector_type(4)));

#define VOCAB 100000
#define NB    2048
#define SEQ   50
#define HID   256
#define XIN   512
#define NE    64
#define NP    5

#define OFF_BOW_E 0
#define OFF_BEO_E (NB*NE)
#define OFF_BOW_P (2*NB*NE)
#define OFF_BEO_P (2*NB*NE + NB*NP)

#define AS1(p) ((const __attribute__((address_space(1))) void*)(p))
#define AS3(p) ((__attribute__((address_space(3))) void*)(p))

// ================= bow kernel: 1024 threads (16 waves) per row =============
// R1-R6 lesson: the compiler serializes gather chains at source level no
// matter the structure (VGPR pinned ~52 across 5 attempts). Fix: inline-asm
// global_load_dwordx4 -- opaque to the scheduler, issued back-to-back, one
// s_waitcnt vmcnt(0) for all four => one HBM latency per wave, not four.
#define BOW_T   1024
#define BOW_W   16
#define BOW_TPW 4      // token idx i = w + 16*ii -> 0..63 (i>=SEQ masked off)

__global__ __launch_bounds__(BOW_T, 4) void bow_kernel(
    const int*   __restrict__ s,   const float* __restrict__ Wbh,
    const float* __restrict__ bbh,
    const float* __restrict__ Wbp, const float* __restrict__ bbp,
    const float* __restrict__ Wbe, const float* __restrict__ bbe,
    float* __restrict__ out)
{
    __shared__ float part[BOW_W*HID];   // 16 KB; reused for head partials
    __shared__ float h[HID];
    const int tid  = threadIdx.x;
    const int row  = blockIdx.x;
    const int lane = tid & 63;
    const int w    = tid >> 6;
    const int* srow = s + row*SEQ;

    // lane j holds token j (j<50); others -3 (never matches a valid token)
    int tokl = (lane < SEQ) ? srow[lane] : -3;

    int   tk[BOW_TPW];
    float mk[BOW_TPW];
    #pragma unroll
    for (int ii = 0; ii < BOW_TPW; ++ii) {
        const int i = w + BOW_W*ii;              // this wave's token index
        int t = (i < SEQ) ? srow[i] : -3;
        t = __builtin_amdgcn_readfirstlane(t);
        unsigned long long dup = __ballot(lane < i && tokl == t);
        mk[ii] = (t >= 0 && dup == 0ull) ? 1.0f : 0.0f;  // keep 1st occurrence
        tk[ii] = (t < 0) ? 0 : t;
    }

    // 4 x 1KB row-gathers, pinned with inline asm (cannot be re-serialized)
    const float* wbase = Wbh + (size_t)lane*4;
    const float* a0 = wbase + (size_t)tk[0]*HID;
    const float* a1 = wbase + (size_t)tk[1]*HID;
    const float* a2 = wbase + (size_t)tk[2]*HID;
    const float* a3 = wbase + (size_t)tk[3]*HID;
    f32x4 v0, v1, v2, v3;
    asm volatile("global_load_dwordx4 %0, %1, off" : "=v"(v0) : "v"(a0));
    asm volatile("global_load_dwordx4 %0, %1, off" : "=v"(v1) : "v"(a1));
    asm volatile("global_load_dwordx4 %0, %1, off" : "=v"(v2) : "v"(a2));
    asm volatile("global_load_dwordx4 %0, %1, off" : "=v"(v3) : "v"(a3));
    asm volatile("s_waitcnt vmcnt(0)" ::: "memory");
    __builtin_amdgcn_sched_barrier(0);           // rule #18: pin consumers

    float ax=0.f, ay=0.f, az=0.f, aw_=0.f;
    ax = fmaf(mk[0], v0[0], ax); ay = fmaf(mk[0], v0[1], ay);
    az = fmaf(mk[0], v0[2], az); aw_= fmaf(mk[0], v0[3], aw_);
    ax = fmaf(mk[1], v1[0], ax); ay = fmaf(mk[1], v1[1], ay);
    az = fmaf(mk[1], v1[2], az); aw_= fmaf(mk[1], v1[3], aw_);
    ax = fmaf(mk[2], v2[0], ax); ay = fmaf(mk[2], v2[1], ay);
    az = fmaf(mk[2], v2[2], az); aw_= fmaf(mk[2], v2[3], aw_);
    ax = fmaf(mk[3], v3[0], ax); ay = fmaf(mk[3], v3[1], ay);
    az = fmaf(mk[3], v3[2], az); aw_= fmaf(mk[3], v3[3], aw_);

    *(float4*)&part[w*HID + lane*4] = make_float4(ax, ay, az, aw_);
    __syncthreads();

    if (tid < HID) {
        float hv = bbh[tid];
        #pragma unroll
        for (int p = 0; p < BOW_W; ++p) hv += part[p*HID + tid];
        hv = hv > 0.f ? hv : 0.2f*hv;
        h[tid] = hv;
    }
    __syncthreads();

    // embd head: 64 outs x 16 partials = 1024 threads
    {
        const int jj = tid & 63, p2 = tid >> 6;   // p2 in 0..15
        float ps = 0.f;
        #pragma unroll
        for (int kk = 0; kk < 16; ++kk) {
            int k = p2*16 + kk;
            ps = fmaf(h[k], Wbe[k*NE + jj], ps);
        }
        part[tid] = ps;                           // flat [p2*64+jj]
    }
    // pred partials: 5 outs x 8 partials (threads 0..39)
    float pp = 0.f;
    if (tid < 8*NP) {
        const int p = tid / NP, jj = tid % NP;
        #pragma unroll 8
        for (int kk = 0; kk < 32; ++kk) {
            int k = p*32 + kk;
            pp = fmaf(h[k], Wbp[k*NP + jj], pp);
        }
    }
    __syncthreads();
    if (tid < NE) {
        float e = bbe[tid];
        #pragma unroll
        for (int p2 = 0; p2 < 16; ++p2) e += part[p2*64 + tid];
        out[OFF_BOW_E + (size_t)row*NE + tid] = e;
    }
    __syncthreads();                              // part free again
    if (tid < 8*NP) part[tid] = pp;
    __syncthreads();
    if (tid < NP) {
        float sp = bbp[tid];
        #pragma unroll
        for (int q = 0; q < 8; ++q) sp += part[q*NP + tid];
        out[OFF_BOW_P + (size_t)row*NP + tid] = sp;
    }
}

// ================= beo kernel: LDS-tiled GEMM (m97-style 2-phase) ==========
// R6 postmortem: 1-block/CU latency chain = 62us. New shape: 512 blocks
// (4 rows x 256 cols, 2 blocks/CU), W k-tiles (32x256=32KB) double-buffered
// via global_load_lds width-16 prefetch; x transposed in LDS so inner loop =
// 1 conflict-free ds_read_b32 + 1 broadcast b128 + 4 fma per k.
#define BEO_RPB 4
#define BEO_BK  32
#define BEO_NT  (XIN/BEO_BK)     // 16 k-tiles
#define BEO_GRID (NB/BEO_RPB)    // 512 blocks

__global__ __launch_bounds__(256, 2) void beo_kernel(
    const float* __restrict__ x,
    const float* __restrict__ Weh, const float* __restrict__ beh,
    const float* __restrict__ Wep, const float* __restrict__ bep,
    const float* __restrict__ Wee, const float* __restrict__ bee,
    float* __restrict__ out)
{
    __shared__ float Wlds[2][BEO_BK*HID];   // 2 x 32KB = 64 KB
    __shared__ float xT[XIN*BEO_RPB];       // x transposed [k][r], 8 KB
    const int tid  = threadIdx.x;
    const int lane = tid & 63;
    const int w    = tid >> 6;
    const int r0   = blockIdx.x * BEO_RPB;

    // stage xT (transpose in registers; coalesced global reads per row)
    {
        float a0 = x[(size_t)(r0+0)*XIN + tid];
        float a1 = x[(size_t)(r0+1)*XIN + tid];
        float a2 = x[(size_t)(r0+2)*XIN + tid];
        float a3 = x[(size_t)(r0+3)*XIN + tid];
        float b0 = x[(size_t)(r0+0)*XIN + 256 + tid];
        float b1 = x[(size_t)(r0+1)*XIN + 256 + tid];
        float b2 = x[(size_t)(r0+2)*XIN + 256 + tid];
        float b3 = x[(size_t)(r0+3)*XIN + 256 + tid];
        *(f32x4*)&xT[(size_t)tid*4]       = (f32x4){a0,a1,a2,a3};
        *(f32x4*)&xT[(size_t)(256+tid)*4] = (f32x4){b0,b1,b2,b3};
    }

    // async stage of W k-tile t into buffer b (wave-uniform LDS base + lane*16)
    auto stage = [&](int t, int b) {
        const size_t tbase = (size_t)t * BEO_BK * HID;
        #pragma unroll
        for (int j = 0; j < 8; ++j) {
            const int off = j*1024 + w*256;        // floats, uniform per wave
            __builtin_amdgcn_global_load_lds(
                AS1(Weh + tbase + off + lane*4),
                AS3(&Wlds[b][off]), 16, 0, 0);
        }
    };

    stage(0, 0);
    asm volatile("s_waitcnt vmcnt(0)" ::: "memory");
    __syncthreads();                               // xT writes + tile0 ready

    float acc0=0.f, acc1=0.f, acc2=0.f, acc3=0.f;
    int buf = 0;
    for (int t = 0; t < BEO_NT; ++t) {
        if (t+1 < BEO_NT) stage(t+1, buf^1);       // prefetch under compute
        const float* wl = &Wlds[buf][0];
        const f32x4* xt = (const f32x4*)&xT[(size_t)t*BEO_BK*4];
        #pragma unroll 8
        for (int k = 0; k < BEO_BK; ++k) {
            float wv = wl[k*HID + tid];            // conflict-free b32
            f32x4 xv = xt[k];                      // broadcast b128 (4 rows)
            acc0 = fmaf(xv[0], wv, acc0);
            acc1 = fmaf(xv[1], wv, acc1);
            acc2 = fmaf(xv[2], wv, acc2);
            acc3 = fmaf(xv[3], wv, acc3);
        }
        asm volatile("s_waitcnt vmcnt(0)" ::: "memory");
        __syncthreads();                           // next tile landed
        buf ^= 1;
    }

    // bias + leaky; reuse xT as hs[4][256]
    float bv = beh[tid];
    float h0 = acc0 + bv; h0 = h0 > 0.f ? h0 : 0.2f*h0;
    float h1 = acc1 + bv; h1 = h1 > 0.f ? h1 : 0.2f*h1;
    float h2 = acc2 + bv; h2 = h2 > 0.f ? h2 : 0.2f*h2;
    float h3 = acc3 + bv; h3 = h3 > 0.f ? h3 : 0.2f*h3;
    float* hs = xT;
    hs[0*HID + tid] = h0;
    hs[1*HID + tid] = h1;
    hs[2*HID + tid] = h2;
    hs[3*HID + tid] = h3;
    __syncthreads();

    // embd head: 4 rows x 64 cols -> 1 output per thread
    {
        const int jj = tid & 63, r = tid >> 6;
        const f32x4* h4 = (const f32x4*)&hs[r*HID];
        float s0 = 0.f;
        #pragma unroll 4
        for (int k4 = 0; k4 < HID/4; ++k4) {
            f32x4 hv = h4[k4];
            const float* wp = Wee + (size_t)(4*k4)*NE + jj;
            s0 = fmaf(hv[0], wp[0],    s0);
            s0 = fmaf(hv[1], wp[NE],   s0);
            s0 = fmaf(hv[2], wp[2*NE], s0);
            s0 = fmaf(hv[3], wp[3*NE], s0);
        }
        out[OFF_BEO_E + (size_t)(r0+r)*NE + jj] = s0 + bee[jj];
    }
    // pred head: 4 rows x 5 cols
    if (tid < BEO_RPB*NP) {
        const int r = tid / NP, jj = tid % NP;
        float sp = bep[jj];
        for (int k = 0; k < HID; ++k)
            sp = fmaf(hs[r*HID + k], Wep[k*NP + jj], sp);
        out[OFF_BEO_P + (size_t)(r0+r)*NP + jj] = sp;
    }
}

extern "C" void kernel_launch(void* const* d_in, const int* in_sizes, int n_in,
                              void* d_out, int out_size, void* d_ws, size_t ws_size,
                              hipStream_t stream) {
    const int*   s   = (const int*)  d_in[0];
    const float* x   = (const float*)d_in[1];
    const float* Wbh = (const float*)d_in[2];
    const float* bbh = (const float*)d_in[3];
    const float* Wbp = (const float*)d_in[4];
    const float* bbp = (const float*)d_in[5];
    const float* Wbe = (const float*)d_in[6];
    const float* bbe = (const float*)d_in[7];
    const float* Weh = (const float*)d_in[8];
    const float* beh = (const float*)d_in[9];
    const float* Wep = (const float*)d_in[10];
    const float* bep = (const float*)d_in[11];
    const float* Wee = (const float*)d_in[12];
    const float* bee = (const float*)d_in[13];
    float* out = (float*)d_out;

    bow_kernel<<<dim3(NB), dim3(BOW_T), 0, stream>>>(
        s, Wbh, bbh, Wbp, bbp, Wbe, bbe, out);
    beo_kernel<<<dim3(BEO_GRID), dim3(256), 0, stream>>>(
        x, Weh, beh, Wep, bep, Wee, bee, out);
}

// Round 8
// 217.684 us; speedup vs baseline: 1.1083x; 1.0667x over previous
//
#include <hip/hip_runtime.h>
#include <cstdint>

typedef float f32x4 __attribute__((ext_vector_type(4)));

#define VOCAB 100000
#define NB    2048
#define SEQ   50
#define HID   256
#define XIN   512
#define NE    64
#define NP    5

#define NBEO  256              // beo blocks (8 rows each)
#define NBLK  (NBEO + NB)

#define OFF_BOW_E 0
#define OFF_BEO_E (NB*NE)
#define OFF_BOW_P (2*NB*NE)
#define OFF_BEO_P (2*NB*NE + NB*NP)

#define GITER 13               // bow: tokens per wave, i = w + 4*ii (0..51)

// Fused kernel, 256 threads/block.
//  blocks 0..255      : beo (8 rows, 4 waves = 4 K-quarters, zero-LDS inner loop)
//  blocks 256..2303   : bow (1 row, 4 waves x 13 asm-pinned 1KB row-gathers)
// beo first so its ~4us of VALU work hides under the bow HBM gather stream.
__global__ __launch_bounds__(256, 2) void fused_kernel(
    const int*   __restrict__ s,   const float* __restrict__ x,
    const float* __restrict__ Wbh, const float* __restrict__ bbh,
    const float* __restrict__ Wbp, const float* __restrict__ bbp,
    const float* __restrict__ Wbe, const float* __restrict__ bbe,
    const float* __restrict__ Weh, const float* __restrict__ beh,
    const float* __restrict__ Wep, const float* __restrict__ bep,
    const float* __restrict__ Wee, const float* __restrict__ bee,
    float* __restrict__ out)
{
    __shared__ float smem[2*8*HID];    // 16 KB; beo: parts[2][8][256]; bow: part[4][256]+h[256]
    const int tid  = threadIdx.x;
    const int blk  = blockIdx.x;
    const int lane = tid & 63;
    const int w    = tid >> 6;

    if (blk < NBEO) {
        // ================= beo: 8 rows, wave w = K-quarter w =================
        // R7 postmortem: LDS broadcast reads (12cyc/16B) made the tiled GEMM
        // LDS-pipe-bound (~30us). Here: W -> registers via coalesced L2-hot
        // loads (no redundancy: each wave reads only its 128-k range), x via
        // block-uniform addresses -> s_load -> v_fmac(sgpr,vgpr). Zero LDS
        // in the inner loop; VALU floor ~8.2k cyc/wave.
        const int r0 = blk * 8;
        f32x4 acc[8];
        #pragma unroll
        for (int r = 0; r < 8; ++r) acc[r] = (f32x4){0.f,0.f,0.f,0.f};

        const int kb0 = w * 128;                    // this wave's K-range
        #pragma unroll 2
        for (int c = 0; c < 16; ++c) {              // 16 chunks of 8 k
            const int kb = kb0 + c*8;
            f32x4 wr[8];
            #pragma unroll
            for (int kk = 0; kk < 8; ++kk)
                wr[kk] = *(const f32x4*)(Weh + (size_t)(kb+kk)*HID + 4*lane);
            #pragma unroll
            for (int r = 0; r < 8; ++r) {
                const float* xrow = x + (size_t)(r0+r)*XIN + kb;  // uniform -> s_load
                #pragma unroll
                for (int kk = 0; kk < 8; ++kk)
                    acc[r] += xrow[kk] * wr[kk];
            }
        }

        // cross-wave K-reduce: parts[2][8][256]
        float* parts0 = smem;                 // [8][256]
        float* parts1 = smem + 8*HID;         // [8][256]
        if (w == 1 || w == 3) {
            float* dst = (w == 1) ? parts0 : parts1;
            #pragma unroll
            for (int r = 0; r < 8; ++r)
                *(f32x4*)&dst[r*HID + 4*lane] = acc[r];
        }
        __syncthreads();
        if (w == 0 || w == 2) {
            float* dst = (w == 0) ? parts0 : parts1;
            #pragma unroll
            for (int r = 0; r < 8; ++r) {
                f32x4 p = *(const f32x4*)&dst[r*HID + 4*lane];
                *(f32x4*)&dst[r*HID + 4*lane] = acc[r] + p;
            }
        }
        __syncthreads();
        // h = leaky(parts0+parts1+bias); store into parts0 slot (per-col, safe)
        {
            float bv = beh[tid];
            #pragma unroll
            for (int r = 0; r < 8; ++r) {
                float hv = parts0[r*HID + tid] + parts1[r*HID + tid] + bv;
                parts0[r*HID + tid] = hv > 0.f ? hv : 0.2f*hv;
            }
        }
        __syncthreads();
        const float* hs = parts0;             // [8][256]

        // embd head: 8 rows x 64 cols -> 2 outputs/thread
        {
            const int jj = tid & 63;
            const int r  = tid >> 6;          // rows r and r+4
            const f32x4* ha4 = (const f32x4*)&hs[r*HID];
            const f32x4* hb4 = (const f32x4*)&hs[(r+4)*HID];
            float s0 = 0.f, s1 = 0.f;
            #pragma unroll 4
            for (int k4 = 0; k4 < HID/4; ++k4) {
                f32x4 ha = ha4[k4], hb = hb4[k4];
                const float* wp = Wee + (size_t)(4*k4)*NE + jj;
                float w0 = wp[0], w1 = wp[NE], w2 = wp[2*NE], w3 = wp[3*NE];
                s0 = fmaf(ha[0], w0, s0); s0 = fmaf(ha[1], w1, s0);
                s0 = fmaf(ha[2], w2, s0); s0 = fmaf(ha[3], w3, s0);
                s1 = fmaf(hb[0], w0, s1); s1 = fmaf(hb[1], w1, s1);
                s1 = fmaf(hb[2], w2, s1); s1 = fmaf(hb[3], w3, s1);
            }
            float bias = bee[jj];
            out[OFF_BEO_E + (size_t)(r0+r)*NE   + jj] = s0 + bias;
            out[OFF_BEO_E + (size_t)(r0+r+4)*NE + jj] = s1 + bias;
        }
        // pred head: 8 rows x 5 cols
        if (tid < 8*NP) {
            const int r = tid / NP, jj = tid % NP;
            float sp = bep[jj];
            for (int k = 0; k < HID; ++k)
                sp = fmaf(hs[r*HID + k], Wep[k*NP + jj], sp);
            out[OFF_BEO_P + (size_t)(r0+r)*NP + jj] = sp;
        }
    } else {
        // ================= bow: 1 row, 4 waves x 13 asm-pinned gathers ========
        const int row  = blk - NBEO;
        const int* srow = s + row*SEQ;
        float* part = smem;                   // [4][256]
        float* hsm  = smem + 4*HID;           // [256]

        // lane j holds token j (j<50); others -3 (never matches)
        int tokl = (lane < SEQ) ? srow[lane] : -3;

        int   tk[GITER];
        float mk[GITER];
        #pragma unroll
        for (int ii = 0; ii < GITER; ++ii) {
            const int i = w + 4*ii;                    // wave's token index
            int t = (i < SEQ) ? srow[i] : -3;          // uniform -> s_load
            t = __builtin_amdgcn_readfirstlane(t);
            unsigned long long dup = __ballot(lane < i && tokl == t);
            mk[ii] = (t >= 0 && dup == 0ull) ? 1.0f : 0.0f;
            tk[ii] = (t < 0) ? 0 : t;
        }

        // 13 x 1KB row-gathers, asm-pinned back-to-back, ONE waitcnt.
        const float* wbase = Wbh + (size_t)lane*4;
        const float* a0  = wbase + (size_t)tk[0]*HID;
        const float* a1  = wbase + (size_t)tk[1]*HID;
        const float* a2  = wbase + (size_t)tk[2]*HID;
        const float* a3  = wbase + (size_t)tk[3]*HID;
        const float* a4  = wbase + (size_t)tk[4]*HID;
        const float* a5  = wbase + (size_t)tk[5]*HID;
        const float* a6  = wbase + (size_t)tk[6]*HID;
        const float* a7  = wbase + (size_t)tk[7]*HID;
        const float* a8  = wbase + (size_t)tk[8]*HID;
        const float* a9  = wbase + (size_t)tk[9]*HID;
        const float* a10 = wbase + (size_t)tk[10]*HID;
        const float* a11 = wbase + (size_t)tk[11]*HID;
        const float* a12 = wbase + (size_t)tk[12]*HID;
        f32x4 v0,v1,v2,v3,v4,v5,v6,v7,v8,v9,v10,v11,v12;
        asm volatile("global_load_dwordx4 %0, %1, off" : "=v"(v0)  : "v"(a0));
        asm volatile("global_load_dwordx4 %0, %1, off" : "=v"(v1)  : "v"(a1));
        asm volatile("global_load_dwordx4 %0, %1, off" : "=v"(v2)  : "v"(a2));
        asm volatile("global_load_dwordx4 %0, %1, off" : "=v"(v3)  : "v"(a3));
        asm volatile("global_load_dwordx4 %0, %1, off" : "=v"(v4)  : "v"(a4));
        asm volatile("global_load_dwordx4 %0, %1, off" : "=v"(v5)  : "v"(a5));
        asm volatile("global_load_dwordx4 %0, %1, off" : "=v"(v6)  : "v"(a6));
        asm volatile("global_load_dwordx4 %0, %1, off" : "=v"(v7)  : "v"(a7));
        asm volatile("global_load_dwordx4 %0, %1, off" : "=v"(v8)  : "v"(a8));
        asm volatile("global_load_dwordx4 %0, %1, off" : "=v"(v9)  : "v"(a9));
        asm volatile("global_load_dwordx4 %0, %1, off" : "=v"(v10) : "v"(a10));
        asm volatile("global_load_dwordx4 %0, %1, off" : "=v"(v11) : "v"(a11));
        asm volatile("global_load_dwordx4 %0, %1, off" : "=v"(v12) : "v"(a12));
        asm volatile("s_waitcnt vmcnt(0)" ::: "memory");
        __builtin_amdgcn_sched_barrier(0);        // rule #18: pin consumers

        f32x4 a = (f32x4){0.f,0.f,0.f,0.f};
        a += mk[0]*v0;   a += mk[1]*v1;   a += mk[2]*v2;   a += mk[3]*v3;
        a += mk[4]*v4;   a += mk[5]*v5;   a += mk[6]*v6;   a += mk[7]*v7;
        a += mk[8]*v8;   a += mk[9]*v9;   a += mk[10]*v10; a += mk[11]*v11;
        a += mk[12]*v12;

        *(f32x4*)&part[w*HID + lane*4] = a;
        __syncthreads();
        {
            float hv = part[tid] + part[HID + tid]
                     + part[2*HID + tid] + part[3*HID + tid] + bbh[tid];
            hsm[tid] = hv > 0.f ? hv : 0.2f*hv;
        }
        __syncthreads();

        // embd head: 64 outs x 4 partials
        {
            const int jj = tid & 63, p = tid >> 6;
            const f32x4* h4 = (const f32x4*)hsm;
            float ps = 0.f;
            #pragma unroll 4
            for (int k4 = 0; k4 < 16; ++k4) {
                f32x4 hv = h4[p*16 + k4];
                const float* wp = Wbe + (size_t)(p*64 + 4*k4)*NE + jj;
                ps = fmaf(hv[0], wp[0],    ps);
                ps = fmaf(hv[1], wp[NE],   ps);
                ps = fmaf(hv[2], wp[2*NE], ps);
                ps = fmaf(hv[3], wp[3*NE], ps);
            }
            part[tid] = ps;
        }
        // pred partials: 5 outs x 8 partials (threads 0..39), reads hsm only
        float pp = 0.f;
        if (tid < 8*NP) {
            const int p = tid / NP, jj = tid % NP;
            #pragma unroll 8
            for (int kk = 0; kk < 32; ++kk) {
                int k = p*32 + kk;
                pp = fmaf(hsm[k], Wbp[k*NP + jj], pp);
            }
        }
        __syncthreads();
        if (tid < NE) {
            float e = part[tid] + part[tid+64]
                    + part[tid+128] + part[tid+192] + bbe[tid];
            out[OFF_BOW_E + (size_t)row*NE + tid] = e;
        }
        __syncthreads();
        if (tid < 8*NP) part[tid] = pp;
        __syncthreads();
        if (tid < NP) {
            float sp = bbp[tid];
            #pragma unroll
            for (int q = 0; q < 8; ++q) sp += part[q*NP + tid];
            out[OFF_BOW_P + (size_t)row*NP + tid] = sp;
        }
    }
}

extern "C" void kernel_launch(void* const* d_in, const int* in_sizes, int n_in,
                              void* d_out, int out_size, void* d_ws, size_t ws_size,
                              hipStream_t stream) {
    const int*   s   = (const int*)  d_in[0];
    const float* x   = (const float*)d_in[1];
    const float* Wbh = (const float*)d_in[2];
    const float* bbh = (const float*)d_in[3];
    const float* Wbp = (const float*)d_in[4];
    const float* bbp = (const float*)d_in[5];
    const float* Wbe = (const float*)d_in[6];
    const float* bbe = (const float*)d_in[7];
    const float* Weh = (const float*)d_in[8];
    const float* beh = (const float*)d_in[9];
    const float* Wep = (const float*)d_in[10];
    const float* bep = (const float*)d_in[11];
    const float* Wee = (const float*)d_in[12];
    const float* bee = (const float*)d_in[13];

    fused_kernel<<<dim3(NBLK), dim3(256), 0, stream>>>(
        s, x, Wbh, bbh, Wbp, bbp, Wbe, bbe,
        Weh, beh, Wep, bep, Wee, bee, (float*)d_out);
}